// Round 2
// baseline (261.680 us; speedup 1.0000x reference)
//
#include <hip/hip_runtime.h>

// SpikeDrivenTransformer block, MI355X. T=4 B=16 C=512 H=W=16 (N=256), HEADS=8.
// ALL inputs/outputs are fp32 (reference is jnp.float32 throughout).
// All post-LIF tensors are binary -> conv1x1 becomes sparse column-sums.
// Kernels:
//  k0_transpose : q_w/k_w/v_w -> wqkv_t[c][1536], proj_w -> pwt[c][512] (fp32)
//  k0_bn        : fold BN (and proj bias) into per-channel inv/shift (fp32)
//  k1_lif_x     : LIF over t on x, LDS-transpose, pack 4 t-bits -> xs_mask[b][n][c]
//  k2_qkv       : per (b,n) column: active-list sparse accumulate q/k/v (fp32),
//                 fused BN + LIF -> q_mask[b][n][c], (k&v)-mask[b][n][c]
//  k3_kv        : popcount over n + exact-integer LIF(v_th=0.5) -> kvs_mask[b][c]
//  k4_attn_proj : per (b,n) column: (q & kv_s) sparse proj GEMM + BN -> y_t[t][b][n][o] fp32
//  k5_out       : LDS-transpose y_t back to [t][b][o][n], add identity x, fp32 out

#define T_  4
#define B_  16
#define C_  512
#define N_  256
#define O3_ 1536
#define EPS_ 1e-5f

// ---------------- k0a: weight transposes ----------------
__global__ void k0_transpose(const float* __restrict__ qw, const float* __restrict__ kw,
                             const float* __restrict__ vw, const float* __restrict__ pw,
                             float* __restrict__ wqkv_t, float* __restrict__ pwt){
    int idx = blockIdx.x * 256 + threadIdx.x;      // grid covers exactly C*O3 + C*C
    if (idx < C_ * O3_) {
        int c = idx / O3_, o = idx % O3_;
        const float* src = (o < 512) ? qw : (o < 1024 ? kw : vw);
        int oo = o & 511;
        wqkv_t[idx] = src[oo * C_ + c];
    } else {
        int j = idx - C_ * O3_;                    // < C*C
        int c = j >> 9, o = j & 511;
        pwt[j] = pw[o * C_ + c];
    }
}

// ---------------- k0b: BN constant folding ----------------
// bnc layout (fp32): [g*1024 + ch] = inv, [g*1024 + 512 + ch] = shift, g=0(q),1(k),2(v)
//                    [3072 + o] = inv_p, [3584 + o] = proj_b*inv_p + shift_p
__global__ void k0_bn(const float* qg,const float* qb,const float* qm,const float* qv,
                      const float* kg,const float* kb,const float* km,const float* kvr,
                      const float* vg,const float* vb,const float* vm,const float* vv,
                      const float* pg,const float* pb2,const float* pm,const float* pv,
                      const float* projb, float* __restrict__ bnc){
    int ch = blockIdx.x * 256 + threadIdx.x;
    if (ch >= C_) return;
    {   float inv = qg[ch] / sqrtf(qv[ch] + EPS_);
        bnc[ch] = inv;            bnc[512 + ch]  = qb[ch] - qm[ch] * inv; }
    {   float inv = kg[ch] / sqrtf(kvr[ch] + EPS_);
        bnc[1024 + ch] = inv;     bnc[1536 + ch] = kb[ch] - km[ch] * inv; }
    {   float inv = vg[ch] / sqrtf(vv[ch] + EPS_);
        bnc[2048 + ch] = inv;     bnc[2560 + ch] = vb[ch] - vm[ch] * inv; }
    {   float inv = pg[ch] / sqrtf(pv[ch] + EPS_);
        float shift = pb2[ch] - pm[ch] * inv;
        bnc[3072 + ch] = inv;     bnc[3584 + ch] = projb[ch] * inv + shift; }
}

// ---------------- k1: LIF(x) + transpose-pack ----------------
// grid (B, C/64, N/64), block 256. xs_mask[b][n][c] byte holds 4 t-bits.
__global__ void k1_lif_x(const float* __restrict__ x, unsigned char* __restrict__ xs_mask){
    __shared__ unsigned char sm[64 * 68];          // row stride 68: conflict-free both phases
    int b = blockIdx.x, c0 = blockIdx.y * 64, n0 = blockIdx.z * 64;
    int tid = threadIdx.x;
    #pragma unroll
    for (int i = 0; i < 16; i++) {
        int idx = i * 256 + tid;
        int nl = idx & 63, cl = idx >> 6;          // lanes -> consecutive n (coalesced)
        const float* xp = x + ((size_t)b * C_ + c0 + cl) * N_ + n0 + nl;
        float v = 0.f; unsigned m = 0;
        #pragma unroll
        for (int t = 0; t < T_; t++) {
            float xt = xp[(size_t)t * B_ * C_ * N_];
            v = v + (xt - v) * 0.5f;               // v += (x - v)/TAU, TAU=2
            if (v - 1.0f >= 0.f) { m |= 1u << t; v = 0.f; }   // spike(v - v_th), hard reset
        }
        sm[cl * 68 + nl] = (unsigned char)m;
    }
    __syncthreads();
    #pragma unroll
    for (int i = 0; i < 16; i++) {
        int idx = i * 256 + tid;
        int cl = idx & 63, nl = idx >> 6;          // lanes -> consecutive c (coalesced)
        xs_mask[((size_t)b * N_ + n0 + nl) * C_ + c0 + cl] = sm[cl * 68 + nl];
    }
}

// ---------------- k2: sparse qkv GEMM + BN + LIF ----------------
// grid (N, B), block 256. Each thread owns channel pair (2*tid, 2*tid+1) for q,k,v.
__global__ void k2_qkv(const unsigned char* __restrict__ xs_mask,
                       const float* __restrict__ wqkv_t,
                       const float* __restrict__ bnc,
                       unsigned char* __restrict__ q_mask,
                       unsigned char* __restrict__ kvand_mask){
    __shared__ unsigned char sm[512];
    __shared__ unsigned int  scnt;
    __shared__ unsigned int  slist[512];
    int n = blockIdx.x, b = blockIdx.y, tid = threadIdx.x;
    size_t colbase = ((size_t)b * N_ + n) * C_;
    sm[tid]       = xs_mask[colbase + tid];
    sm[tid + 256] = xs_mask[colbase + tid + 256];
    if (tid == 0) scnt = 0;
    __syncthreads();
    #pragma unroll
    for (int h = 0; h < 2; h++) {
        int c = tid + (h << 8);
        unsigned m = sm[c];
        if (m) { unsigned p = atomicAdd(&scnt, 1u); slist[p] = (unsigned)c | (m << 16); }
    }
    __syncthreads();
    int cnt = scnt;

    float acc[4][6];                               // [t][g*2+e], g=0 q,1 k,2 v
    #pragma unroll
    for (int t = 0; t < 4; t++)
        #pragma unroll
        for (int k = 0; k < 6; k++) acc[t][k] = 0.f;

    for (int j = 0; j < cnt; j++) {
        unsigned e = slist[j];
        int c = e & 0xffff; unsigned m = e >> 16;
        const float2* wp = reinterpret_cast<const float2*>(wqkv_t + (size_t)c * O3_);
        float2 wv[3];
        #pragma unroll
        for (int g = 0; g < 3; g++) wv[g] = wp[g * 256 + tid];
        #pragma unroll
        for (int t = 0; t < 4; t++) {
            if (m & (1u << t)) {                   // block-uniform branch
                #pragma unroll
                for (int g = 0; g < 3; g++) { acc[t][g*2] += wv[g].x; acc[t][g*2+1] += wv[g].y; }
            }
        }
    }

    unsigned kbits[2] = {0, 0};
    #pragma unroll
    for (int g = 0; g < 3; g++) {
        #pragma unroll
        for (int e2 = 0; e2 < 2; e2++) {
            int ch = 2 * tid + e2;
            float inv = bnc[g * 1024 + ch];
            float sh  = bnc[g * 1024 + 512 + ch];
            float v = 0.f; unsigned bits = 0;
            #pragma unroll
            for (int t = 0; t < 4; t++) {
                float pre = acc[t][g*2+e2] * inv + sh;       // BN
                v = v + (pre - v) * 0.5f;                    // LIF
                if (v - 1.0f >= 0.f) { bits |= 1u << t; v = 0.f; }
            }
            if (g == 0)      q_mask[colbase + ch] = (unsigned char)bits;
            else if (g == 1) kbits[e2] = bits;
            else             kvand_mask[colbase + ch] = (unsigned char)(bits & kbits[e2]);
        }
    }
}

// ---------------- k3: kv popcount over n + exact LIF ----------------
// grid (2, B), block 256 (lane = channel).
__global__ void k3_kv(const unsigned char* __restrict__ kvand_mask,
                      unsigned char* __restrict__ kvs_mask){
    int c = blockIdx.x * 256 + threadIdx.x;
    int b = blockIdx.y;
    int cnt[4] = {0, 0, 0, 0};
    const unsigned char* p = kvand_mask + (size_t)b * N_ * C_ + c;
    for (int n = 0; n < N_; n++) {
        unsigned m = p[(size_t)n * C_];
        #pragma unroll
        for (int t = 0; t < 4; t++) cnt[t] += (m >> t) & 1;
    }
    float v = 0.f; unsigned bits = 0;
    #pragma unroll
    for (int t = 0; t < 4; t++) {
        float kvf = (float)cnt[t];                 // counts exact in fp32
        v = v + (kvf - v) * 0.5f;                  // halving of integers: exact
        if (v - 0.5f >= 0.f) { bits |= 1u << t; v = 0.f; }
    }
    kvs_mask[b * C_ + c] = (unsigned char)bits;
}

// ---------------- k4: sparse proj GEMM (attn = q & kv_s) + BN ----------------
// grid (N, B), block 256. Output y_t[t][b][n][o] fp32 (coalesced in o).
__global__ void k4_attn_proj(const unsigned char* __restrict__ q_mask,
                             const unsigned char* __restrict__ kvs_mask,
                             const float* __restrict__ pwt,
                             const float* __restrict__ bnc,
                             float* __restrict__ y_t){
    __shared__ unsigned char sm[512];
    __shared__ unsigned int  scnt;
    __shared__ unsigned int  slist[512];
    int n = blockIdx.x, b = blockIdx.y, tid = threadIdx.x;
    size_t colbase = ((size_t)b * N_ + n) * C_;
    sm[tid]       = (unsigned char)(q_mask[colbase + tid]       & kvs_mask[b * C_ + tid]);
    sm[tid + 256] = (unsigned char)(q_mask[colbase + tid + 256] & kvs_mask[b * C_ + tid + 256]);
    if (tid == 0) scnt = 0;
    __syncthreads();
    #pragma unroll
    for (int h = 0; h < 2; h++) {
        int c = tid + (h << 8);
        unsigned m = sm[c];
        if (m) { unsigned p = atomicAdd(&scnt, 1u); slist[p] = (unsigned)c | (m << 16); }
    }
    __syncthreads();
    int cnt = scnt;

    float acc[4][2];
    #pragma unroll
    for (int t = 0; t < 4; t++) { acc[t][0] = 0.f; acc[t][1] = 0.f; }

    for (int j = 0; j < cnt; j++) {
        unsigned e = slist[j];
        int c = e & 0xffff; unsigned m = e >> 16;
        float2 w = reinterpret_cast<const float2*>(pwt + (size_t)c * C_)[tid];
        #pragma unroll
        for (int t = 0; t < 4; t++) {
            if (m & (1u << t)) { acc[t][0] += w.x; acc[t][1] += w.y; }
        }
    }

    float inv0 = bnc[3072 + 2 * tid],     inv1 = bnc[3072 + 2 * tid + 1];
    float sh0  = bnc[3584 + 2 * tid],     sh1  = bnc[3584 + 2 * tid + 1];
    #pragma unroll
    for (int t = 0; t < 4; t++) {
        float2 y2;
        y2.x = acc[t][0] * inv0 + sh0;
        y2.y = acc[t][1] * inv1 + sh1;
        *reinterpret_cast<float2*>(y_t + (((size_t)t * B_ + b) * N_ + n) * C_ + 2 * tid) = y2;
    }
}

// ---------------- k5: transpose back + identity add ----------------
// grid (B, C/64, N/64), block 256.
__global__ void k5_out(const float* __restrict__ y_t, const float* __restrict__ x,
                       float* __restrict__ out){
    __shared__ float tile[64 * 65];
    int b = blockIdx.x, o0 = blockIdx.y * 64, n0 = blockIdx.z * 64;
    int tid = threadIdx.x;
    for (int t = 0; t < T_; t++) {
        __syncthreads();
        #pragma unroll
        for (int i = 0; i < 16; i++) {
            int idx = i * 256 + tid;
            int ol = idx & 63, nl = idx >> 6;      // lanes -> consecutive o (coalesced read)
            tile[ol * 65 + nl] =
                y_t[(((size_t)t * B_ + b) * N_ + n0 + nl) * C_ + o0 + ol];
        }
        __syncthreads();
        #pragma unroll
        for (int i = 0; i < 16; i++) {
            int idx = i * 256 + tid;
            int nl = idx & 63, ol = idx >> 6;      // lanes -> consecutive n (coalesced write)
            size_t a = (((size_t)t * B_ + b) * C_ + o0 + ol) * N_ + n0 + nl;
            out[a] = tile[ol * 65 + nl] + x[a];
        }
    }
}

extern "C" void kernel_launch(void* const* d_in, const int* in_sizes, int n_in,
                              void* d_out, int out_size, void* d_ws, size_t ws_size,
                              hipStream_t stream){
    const float* x     = (const float*)d_in[0];
    const float* q_w   = (const float*)d_in[1];
    const float* q_g   = (const float*)d_in[2];
    const float* q_b   = (const float*)d_in[3];
    const float* q_m   = (const float*)d_in[4];
    const float* q_v   = (const float*)d_in[5];
    const float* k_w   = (const float*)d_in[6];
    const float* k_g   = (const float*)d_in[7];
    const float* k_b   = (const float*)d_in[8];
    const float* k_m   = (const float*)d_in[9];
    const float* k_v   = (const float*)d_in[10];
    const float* v_w   = (const float*)d_in[11];
    const float* v_g   = (const float*)d_in[12];
    const float* v_b   = (const float*)d_in[13];
    const float* v_m   = (const float*)d_in[14];
    const float* v_v   = (const float*)d_in[15];
    const float* pr_w  = (const float*)d_in[16];
    const float* pr_b  = (const float*)d_in[17];
    const float* p_g   = (const float*)d_in[18];
    const float* p_b2  = (const float*)d_in[19];
    const float* p_m   = (const float*)d_in[20];
    const float* p_v   = (const float*)d_in[21];
    float* out = (float*)d_out;

    char* ws = (char*)d_ws;
    float* wqkv_t          = (float*)(ws + 0);                 // 512*1536*4 = 3,145,728
    float* pwt             = (float*)(ws + 3145728);           // 512*512*4  = 1,048,576
    float* bnc             = (float*)(ws + 4194304);           // 4096 fp32  =    16,384
    unsigned char* xs_mask = (unsigned char*)(ws + 4210688);   // 2,097,152
    unsigned char* q_mask  = (unsigned char*)(ws + 6307840);   // 2,097,152
    unsigned char* kvand   = (unsigned char*)(ws + 8404992);   // 2,097,152
    unsigned char* kvs     = (unsigned char*)(ws + 10502144);  //     8,192
    float* y_t             = (float*)(ws + 10510336);          // 33,554,432 -> total ~44 MB

    hipLaunchKernelGGL(k0_transpose, dim3((C_*O3_ + C_*C_)/256), dim3(256), 0, stream,
                       q_w, k_w, v_w, pr_w, wqkv_t, pwt);
    hipLaunchKernelGGL(k0_bn, dim3(2), dim3(256), 0, stream,
                       q_g,q_b,q_m,q_v, k_g,k_b,k_m,k_v, v_g,v_b,v_m,v_v,
                       p_g,p_b2,p_m,p_v, pr_b, bnc);
    hipLaunchKernelGGL(k1_lif_x, dim3(B_, C_/64, N_/64), dim3(256), 0, stream, x, xs_mask);
    hipLaunchKernelGGL(k2_qkv, dim3(N_, B_), dim3(256), 0, stream,
                       xs_mask, wqkv_t, bnc, q_mask, kvand);
    hipLaunchKernelGGL(k3_kv, dim3(2, B_), dim3(256), 0, stream, kvand, kvs);
    hipLaunchKernelGGL(k4_attn_proj, dim3(N_, B_), dim3(256), 0, stream,
                       q_mask, kvs, pwt, bnc, y_t);
    hipLaunchKernelGGL(k5_out, dim3(B_, C_/64, N_/64), dim3(256), 0, stream, y_t, x, out);
}

// Round 3
// 256.172 us; speedup vs baseline: 1.0215x; 1.0215x over previous
//
#include <hip/hip_runtime.h>

// SpikeDrivenTransformer block, MI355X. T=4 B=16 C=512 H=W=16 (N=256), HEADS=8.
// ALL inputs/outputs fp32. All post-LIF tensors are binary -> conv1x1 becomes
// sparse column-sums over an active-channel list.
// R2 change: sparse loops scalarized (readfirstlane -> SGPR c/m, scalar branches)
// + 2x/4x unroll; k0a+k0b merged.

#define T_  4
#define B_  16
#define C_  512
#define N_  256
#define O3_ 1536
#define EPS_ 1e-5f

// ---------------- k0: weight transposes + BN constant folding ----------------
// bnc layout (fp32): [g*1024 + ch] = inv, [g*1024 + 512 + ch] = shift, g=0(q),1(k),2(v)
//                    [3072 + o] = inv_p, [3584 + o] = proj_b*inv_p + shift_p
__global__ void k0_prep(const float* __restrict__ qw, const float* __restrict__ kw,
                        const float* __restrict__ vw, const float* __restrict__ pw,
                        const float* qg,const float* qb,const float* qm,const float* qv,
                        const float* kg,const float* kb,const float* km,const float* kvr,
                        const float* vg,const float* vb,const float* vm,const float* vv,
                        const float* pg,const float* pb2,const float* pm,const float* pv,
                        const float* projb,
                        float* __restrict__ wqkv_t, float* __restrict__ pwt,
                        float* __restrict__ bnc){
    int idx = blockIdx.x * 256 + threadIdx.x;
    if (idx < C_ * O3_) {
        int c = idx / O3_, o = idx % O3_;
        const float* src = (o < 512) ? qw : (o < 1024 ? kw : vw);
        int oo = o & 511;
        wqkv_t[idx] = src[oo * C_ + c];
    } else if (idx < C_ * O3_ + C_ * C_) {
        int j = idx - C_ * O3_;
        int c = j >> 9, o = j & 511;
        pwt[j] = pw[o * C_ + c];
    } else {
        int ch = idx - (C_ * O3_ + C_ * C_);
        if (ch < C_) {
            {   float inv = qg[ch] / sqrtf(qv[ch] + EPS_);
                bnc[ch] = inv;            bnc[512 + ch]  = qb[ch] - qm[ch] * inv; }
            {   float inv = kg[ch] / sqrtf(kvr[ch] + EPS_);
                bnc[1024 + ch] = inv;     bnc[1536 + ch] = kb[ch] - km[ch] * inv; }
            {   float inv = vg[ch] / sqrtf(vv[ch] + EPS_);
                bnc[2048 + ch] = inv;     bnc[2560 + ch] = vb[ch] - vm[ch] * inv; }
            {   float inv = pg[ch] / sqrtf(pv[ch] + EPS_);
                float shift = pb2[ch] - pm[ch] * inv;
                bnc[3072 + ch] = inv;     bnc[3584 + ch] = projb[ch] * inv + shift; }
        }
    }
}

// ---------------- k1: LIF(x) + transpose-pack ----------------
// grid (B, C/64, N/64), block 256. xs_mask[b][n][c] byte holds 4 t-bits.
__global__ void k1_lif_x(const float* __restrict__ x, unsigned char* __restrict__ xs_mask){
    __shared__ unsigned char sm[64 * 68];
    int b = blockIdx.x, c0 = blockIdx.y * 64, n0 = blockIdx.z * 64;
    int tid = threadIdx.x;
    #pragma unroll
    for (int i = 0; i < 16; i++) {
        int idx = i * 256 + tid;
        int nl = idx & 63, cl = idx >> 6;          // lanes -> consecutive n (coalesced)
        const float* xp = x + ((size_t)b * C_ + c0 + cl) * N_ + n0 + nl;
        float v = 0.f; unsigned m = 0;
        #pragma unroll
        for (int t = 0; t < T_; t++) {
            float xt = xp[(size_t)t * B_ * C_ * N_];
            v = v + (xt - v) * 0.5f;               // v += (x - v)/TAU, TAU=2
            if (v - 1.0f >= 0.f) { m |= 1u << t; v = 0.f; }
        }
        sm[cl * 68 + nl] = (unsigned char)m;
    }
    __syncthreads();
    #pragma unroll
    for (int i = 0; i < 16; i++) {
        int idx = i * 256 + tid;
        int cl = idx & 63, nl = idx >> 6;          // lanes -> consecutive c (coalesced)
        xs_mask[((size_t)b * N_ + n0 + nl) * C_ + c0 + cl] = sm[cl * 68 + nl];
    }
}

// ---------------- k2: sparse qkv GEMM + BN + LIF (scalarized list) ----------------
// grid (N, B), block 256. Thread owns channel pair (2*tid, 2*tid+1) for q,k,v.
__global__ void k2_qkv(const unsigned char* __restrict__ xs_mask,
                       const float* __restrict__ wqkv_t,
                       const float* __restrict__ bnc,
                       unsigned char* __restrict__ q_mask,
                       unsigned char* __restrict__ kvand_mask){
    __shared__ unsigned char sm[512];
    __shared__ unsigned int  scnt;
    __shared__ unsigned int  slist[512];
    int n = blockIdx.x, b = blockIdx.y, tid = threadIdx.x;
    size_t colbase = ((size_t)b * N_ + n) * C_;
    sm[tid]       = xs_mask[colbase + tid];
    sm[tid + 256] = xs_mask[colbase + tid + 256];
    if (tid == 0) scnt = 0;
    __syncthreads();
    #pragma unroll
    for (int h = 0; h < 2; h++) {
        int c = tid + (h << 8);
        unsigned m = sm[c];
        if (m) { unsigned p = atomicAdd(&scnt, 1u); slist[p] = (unsigned)c | (m << 16); }
    }
    __syncthreads();
    int cnt = scnt;

    float acc[4][6];                               // [t][g*2+e], g=0 q,1 k,2 v
    #pragma unroll
    for (int t = 0; t < 4; t++)
        #pragma unroll
        for (int k = 0; k < 6; k++) acc[t][k] = 0.f;

#define ACC6(t, wA, wB, wC) { acc[t][0]+=wA.x; acc[t][1]+=wA.y; acc[t][2]+=wB.x; \
                              acc[t][3]+=wB.y; acc[t][4]+=wC.x; acc[t][5]+=wC.y; }
    int j = 0;
    for (; j + 2 <= cnt; j += 2) {
        unsigned e0 = __builtin_amdgcn_readfirstlane(slist[j]);
        unsigned e1 = __builtin_amdgcn_readfirstlane(slist[j + 1]);
        const float2* wp0 = reinterpret_cast<const float2*>(wqkv_t + (size_t)(e0 & 0xffffu) * O3_) + tid;
        const float2* wp1 = reinterpret_cast<const float2*>(wqkv_t + (size_t)(e1 & 0xffffu) * O3_) + tid;
        float2 a0 = wp0[0], a1 = wp0[256], a2 = wp0[512];
        float2 b0 = wp1[0], b1 = wp1[256], b2 = wp1[512];
        unsigned m0 = e0 >> 16, m1 = e1 >> 16;
        if (m0 & 1u) ACC6(0, a0, a1, a2)
        if (m0 & 2u) ACC6(1, a0, a1, a2)
        if (m0 & 4u) ACC6(2, a0, a1, a2)
        if (m0 & 8u) ACC6(3, a0, a1, a2)
        if (m1 & 1u) ACC6(0, b0, b1, b2)
        if (m1 & 2u) ACC6(1, b0, b1, b2)
        if (m1 & 4u) ACC6(2, b0, b1, b2)
        if (m1 & 8u) ACC6(3, b0, b1, b2)
    }
    if (j < cnt) {
        unsigned e0 = __builtin_amdgcn_readfirstlane(slist[j]);
        const float2* wp0 = reinterpret_cast<const float2*>(wqkv_t + (size_t)(e0 & 0xffffu) * O3_) + tid;
        float2 a0 = wp0[0], a1 = wp0[256], a2 = wp0[512];
        unsigned m0 = e0 >> 16;
        if (m0 & 1u) ACC6(0, a0, a1, a2)
        if (m0 & 2u) ACC6(1, a0, a1, a2)
        if (m0 & 4u) ACC6(2, a0, a1, a2)
        if (m0 & 8u) ACC6(3, a0, a1, a2)
    }
#undef ACC6

    unsigned kbits[2] = {0, 0};
    #pragma unroll
    for (int g = 0; g < 3; g++) {
        #pragma unroll
        for (int e2 = 0; e2 < 2; e2++) {
            int ch = 2 * tid + e2;
            float inv = bnc[g * 1024 + ch];
            float sh  = bnc[g * 1024 + 512 + ch];
            float v = 0.f; unsigned bits = 0;
            #pragma unroll
            for (int t = 0; t < 4; t++) {
                float pre = acc[t][g*2+e2] * inv + sh;       // BN
                v = v + (pre - v) * 0.5f;                    // LIF
                if (v - 1.0f >= 0.f) { bits |= 1u << t; v = 0.f; }
            }
            if (g == 0)      q_mask[colbase + ch] = (unsigned char)bits;
            else if (g == 1) kbits[e2] = bits;
            else             kvand_mask[colbase + ch] = (unsigned char)(bits & kbits[e2]);
        }
    }
}

// ---------------- k3: kv popcount over n + exact LIF ----------------
// grid (2, B), block 256 (lane = channel).
__global__ void k3_kv(const unsigned char* __restrict__ kvand_mask,
                      unsigned char* __restrict__ kvs_mask){
    int c = blockIdx.x * 256 + threadIdx.x;
    int b = blockIdx.y;
    int cnt[4] = {0, 0, 0, 0};
    const unsigned char* p = kvand_mask + (size_t)b * N_ * C_ + c;
    for (int n = 0; n < N_; n++) {
        unsigned m = p[(size_t)n * C_];
        #pragma unroll
        for (int t = 0; t < 4; t++) cnt[t] += (m >> t) & 1;
    }
    float v = 0.f; unsigned bits = 0;
    #pragma unroll
    for (int t = 0; t < 4; t++) {
        float kvf = (float)cnt[t];                 // counts exact in fp32
        v = v + (kvf - v) * 0.5f;
        if (v - 0.5f >= 0.f) { bits |= 1u << t; v = 0.f; }
    }
    kvs_mask[b * C_ + c] = (unsigned char)bits;
}

// ---------------- k4: sparse proj GEMM (attn = q & kv_s) + BN (scalarized) ----------------
// grid (N, B), block 256. Output y_t[t][b][n][o] fp32 (coalesced in o).
__global__ void k4_attn_proj(const unsigned char* __restrict__ q_mask,
                             const unsigned char* __restrict__ kvs_mask,
                             const float* __restrict__ pwt,
                             const float* __restrict__ bnc,
                             float* __restrict__ y_t){
    __shared__ unsigned char sm[512];
    __shared__ unsigned int  scnt;
    __shared__ unsigned int  slist[512];
    int n = blockIdx.x, b = blockIdx.y, tid = threadIdx.x;
    size_t colbase = ((size_t)b * N_ + n) * C_;
    sm[tid]       = (unsigned char)(q_mask[colbase + tid]       & kvs_mask[b * C_ + tid]);
    sm[tid + 256] = (unsigned char)(q_mask[colbase + tid + 256] & kvs_mask[b * C_ + tid + 256]);
    if (tid == 0) scnt = 0;
    __syncthreads();
    #pragma unroll
    for (int h = 0; h < 2; h++) {
        int c = tid + (h << 8);
        unsigned m = sm[c];
        if (m) { unsigned p = atomicAdd(&scnt, 1u); slist[p] = (unsigned)c | (m << 16); }
    }
    __syncthreads();
    int cnt = scnt;

    float acc[4][2];
    #pragma unroll
    for (int t = 0; t < 4; t++) { acc[t][0] = 0.f; acc[t][1] = 0.f; }

#define ACC2(t, w_) { acc[t][0] += w_.x; acc[t][1] += w_.y; }
    int j = 0;
    for (; j + 4 <= cnt; j += 4) {
        unsigned e0 = __builtin_amdgcn_readfirstlane(slist[j]);
        unsigned e1 = __builtin_amdgcn_readfirstlane(slist[j + 1]);
        unsigned e2 = __builtin_amdgcn_readfirstlane(slist[j + 2]);
        unsigned e3 = __builtin_amdgcn_readfirstlane(slist[j + 3]);
        float2 w0 = reinterpret_cast<const float2*>(pwt + (size_t)(e0 & 0xffffu) * C_)[tid];
        float2 w1 = reinterpret_cast<const float2*>(pwt + (size_t)(e1 & 0xffffu) * C_)[tid];
        float2 w2 = reinterpret_cast<const float2*>(pwt + (size_t)(e2 & 0xffffu) * C_)[tid];
        float2 w3 = reinterpret_cast<const float2*>(pwt + (size_t)(e3 & 0xffffu) * C_)[tid];
        unsigned m0 = e0 >> 16, m1 = e1 >> 16, m2 = e2 >> 16, m3 = e3 >> 16;
        if (m0 & 1u) ACC2(0, w0)  if (m0 & 2u) ACC2(1, w0)
        if (m0 & 4u) ACC2(2, w0)  if (m0 & 8u) ACC2(3, w0)
        if (m1 & 1u) ACC2(0, w1)  if (m1 & 2u) ACC2(1, w1)
        if (m1 & 4u) ACC2(2, w1)  if (m1 & 8u) ACC2(3, w1)
        if (m2 & 1u) ACC2(0, w2)  if (m2 & 2u) ACC2(1, w2)
        if (m2 & 4u) ACC2(2, w2)  if (m2 & 8u) ACC2(3, w2)
        if (m3 & 1u) ACC2(0, w3)  if (m3 & 2u) ACC2(1, w3)
        if (m3 & 4u) ACC2(2, w3)  if (m3 & 8u) ACC2(3, w3)
    }
    for (; j < cnt; j++) {
        unsigned e0 = __builtin_amdgcn_readfirstlane(slist[j]);
        float2 w0 = reinterpret_cast<const float2*>(pwt + (size_t)(e0 & 0xffffu) * C_)[tid];
        unsigned m0 = e0 >> 16;
        if (m0 & 1u) ACC2(0, w0)  if (m0 & 2u) ACC2(1, w0)
        if (m0 & 4u) ACC2(2, w0)  if (m0 & 8u) ACC2(3, w0)
    }
#undef ACC2

    float inv0 = bnc[3072 + 2 * tid],     inv1 = bnc[3072 + 2 * tid + 1];
    float sh0  = bnc[3584 + 2 * tid],     sh1  = bnc[3584 + 2 * tid + 1];
    #pragma unroll
    for (int t = 0; t < 4; t++) {
        float2 y2;
        y2.x = acc[t][0] * inv0 + sh0;
        y2.y = acc[t][1] * inv1 + sh1;
        *reinterpret_cast<float2*>(y_t + (((size_t)t * B_ + b) * N_ + n) * C_ + 2 * tid) = y2;
    }
}

// ---------------- k5: transpose back + identity add ----------------
// grid (B, C/64, N/64), block 256.
__global__ void k5_out(const float* __restrict__ y_t, const float* __restrict__ x,
                       float* __restrict__ out){
    __shared__ float tile[64 * 65];
    int b = blockIdx.x, o0 = blockIdx.y * 64, n0 = blockIdx.z * 64;
    int tid = threadIdx.x;
    for (int t = 0; t < T_; t++) {
        __syncthreads();
        #pragma unroll
        for (int i = 0; i < 16; i++) {
            int idx = i * 256 + tid;
            int ol = idx & 63, nl = idx >> 6;      // lanes -> consecutive o (coalesced read)
            tile[ol * 65 + nl] =
                y_t[(((size_t)t * B_ + b) * N_ + n0 + nl) * C_ + o0 + ol];
        }
        __syncthreads();
        #pragma unroll
        for (int i = 0; i < 16; i++) {
            int idx = i * 256 + tid;
            int nl = idx & 63, ol = idx >> 6;      // lanes -> consecutive n (coalesced write)
            size_t a = (((size_t)t * B_ + b) * C_ + o0 + ol) * N_ + n0 + nl;
            out[a] = tile[ol * 65 + nl] + x[a];
        }
    }
}

extern "C" void kernel_launch(void* const* d_in, const int* in_sizes, int n_in,
                              void* d_out, int out_size, void* d_ws, size_t ws_size,
                              hipStream_t stream){
    const float* x     = (const float*)d_in[0];
    const float* q_w   = (const float*)d_in[1];
    const float* q_g   = (const float*)d_in[2];
    const float* q_b   = (const float*)d_in[3];
    const float* q_m   = (const float*)d_in[4];
    const float* q_v   = (const float*)d_in[5];
    const float* k_w   = (const float*)d_in[6];
    const float* k_g   = (const float*)d_in[7];
    const float* k_b   = (const float*)d_in[8];
    const float* k_m   = (const float*)d_in[9];
    const float* k_v   = (const float*)d_in[10];
    const float* v_w   = (const float*)d_in[11];
    const float* v_g   = (const float*)d_in[12];
    const float* v_b   = (const float*)d_in[13];
    const float* v_m   = (const float*)d_in[14];
    const float* v_v   = (const float*)d_in[15];
    const float* pr_w  = (const float*)d_in[16];
    const float* pr_b  = (const float*)d_in[17];
    const float* p_g   = (const float*)d_in[18];
    const float* p_b2  = (const float*)d_in[19];
    const float* p_m   = (const float*)d_in[20];
    const float* p_v   = (const float*)d_in[21];
    float* out = (float*)d_out;

    char* ws = (char*)d_ws;
    float* wqkv_t          = (float*)(ws + 0);                 // 3,145,728
    float* pwt             = (float*)(ws + 3145728);           // 1,048,576
    float* bnc             = (float*)(ws + 4194304);           //    16,384
    unsigned char* xs_mask = (unsigned char*)(ws + 4210688);   // 2,097,152
    unsigned char* q_mask  = (unsigned char*)(ws + 6307840);   // 2,097,152
    unsigned char* kvand   = (unsigned char*)(ws + 8404992);   // 2,097,152
    unsigned char* kvs     = (unsigned char*)(ws + 10502144);  //     8,192
    float* y_t             = (float*)(ws + 10510336);          // 33,554,432 -> ~44 MB

    hipLaunchKernelGGL(k0_prep, dim3(4098), dim3(256), 0, stream,
                       q_w, k_w, v_w, pr_w,
                       q_g,q_b,q_m,q_v, k_g,k_b,k_m,k_v, v_g,v_b,v_m,v_v,
                       p_g,p_b2,p_m,p_v, pr_b, wqkv_t, pwt, bnc);
    hipLaunchKernelGGL(k1_lif_x, dim3(B_, C_/64, N_/64), dim3(256), 0, stream, x, xs_mask);
    hipLaunchKernelGGL(k2_qkv, dim3(N_, B_), dim3(256), 0, stream,
                       xs_mask, wqkv_t, bnc, q_mask, kvand);
    hipLaunchKernelGGL(k3_kv, dim3(2, B_), dim3(256), 0, stream, kvand, kvs);
    hipLaunchKernelGGL(k4_attn_proj, dim3(N_, B_), dim3(256), 0, stream,
                       q_mask, kvs, pwt, bnc, y_t);
    hipLaunchKernelGGL(k5_out, dim3(B_, C_/64, N_/64), dim3(256), 0, stream, y_t, x, out);
}

// Round 4
// 218.236 us; speedup vs baseline: 1.1991x; 1.1738x over previous
//
#include <hip/hip_runtime.h>

// SpikeDrivenTransformer block, MI355X. T=4 B=16 C=512 H=W=16 (N=256), HEADS=8.
// ALL inputs/outputs fp32. Post-LIF tensors are binary -> conv1x1 = sparse
// column-sums over an active-channel list (scalarized via readfirstlane).
// R3: k2 384-thread/float4-per-thread rows, k4 128-thread/float4, LDS-tiled k0.

#define T_  4
#define B_  16
#define C_  512
#define N_  256
#define O3_ 1536
#define EPS_ 1e-5f

typedef unsigned int uint32;

// ---------------- k0: LDS-tiled weight transposes + BN folding ----------------
// blocks 0..191: q/k/v 64x64 tiles -> wqkv_t[c][1536]; 192..255: proj -> pwt[c][512];
// 256..257: bnc fold.
__global__ void k0_prep(const float* __restrict__ qw, const float* __restrict__ kw,
                        const float* __restrict__ vw, const float* __restrict__ pw,
                        const float* qg,const float* qb,const float* qm,const float* qv,
                        const float* kg,const float* kb,const float* km,const float* kvr,
                        const float* vg,const float* vb,const float* vm,const float* vv,
                        const float* pg,const float* pb2,const float* pm,const float* pv,
                        const float* projb,
                        float* __restrict__ wqkv_t, float* __restrict__ pwt,
                        float* __restrict__ bnc){
    __shared__ float tile[64 * 65];
    int bx = blockIdx.x, tid = threadIdx.x;
    if (bx < 256) {
        const float* src; float* dst; int ocol;
        int tl;
        if (bx < 192) { int g = bx / 64; tl = bx % 64;
            src = (g == 0) ? qw : (g == 1) ? kw : vw;
            dst = wqkv_t; ocol = g * 512;
        } else { tl = bx - 192; src = pw; dst = pwt; ocol = 0; }
        int o0 = (tl >> 3) * 64, c0 = (tl & 7) * 64;
        int dstride = (bx < 192) ? O3_ : C_;
        #pragma unroll
        for (int i = 0; i < 16; i++) {
            int idx = i * 256 + tid;
            int cl = idx & 63, ol = idx >> 6;      // lanes -> consecutive c (coalesced read)
            tile[ol * 65 + cl] = src[(size_t)(o0 + ol) * C_ + c0 + cl];
        }
        __syncthreads();
        #pragma unroll
        for (int i = 0; i < 16; i++) {
            int idx = i * 256 + tid;
            int ol = idx & 63, cl = idx >> 6;      // lanes -> consecutive o (coalesced write)
            dst[(size_t)(c0 + cl) * dstride + ocol + o0 + ol] = tile[ol * 65 + cl];
        }
    } else {
        int ch = (bx - 256) * 256 + tid;
        if (ch < C_) {
            {   float inv = qg[ch] / sqrtf(qv[ch] + EPS_);
                bnc[ch] = inv;            bnc[512 + ch]  = qb[ch] - qm[ch] * inv; }
            {   float inv = kg[ch] / sqrtf(kvr[ch] + EPS_);
                bnc[1024 + ch] = inv;     bnc[1536 + ch] = kb[ch] - km[ch] * inv; }
            {   float inv = vg[ch] / sqrtf(vv[ch] + EPS_);
                bnc[2048 + ch] = inv;     bnc[2560 + ch] = vb[ch] - vm[ch] * inv; }
            {   float inv = pg[ch] / sqrtf(pv[ch] + EPS_);
                float shift = pb2[ch] - pm[ch] * inv;
                bnc[3072 + ch] = inv;     bnc[3584 + ch] = projb[ch] * inv + shift; }
        }
    }
}

// ---------------- k1: LIF(x) + transpose-pack ----------------
// grid (B, C/64, N/64), block 256. xs_mask[b][n][c] byte holds 4 t-bits.
__global__ void k1_lif_x(const float* __restrict__ x, unsigned char* __restrict__ xs_mask){
    __shared__ unsigned char sm[64 * 68];
    int b = blockIdx.x, c0 = blockIdx.y * 64, n0 = blockIdx.z * 64;
    int tid = threadIdx.x;
    #pragma unroll
    for (int i = 0; i < 16; i++) {
        int idx = i * 256 + tid;
        int nl = idx & 63, cl = idx >> 6;          // lanes -> consecutive n (coalesced)
        const float* xp = x + ((size_t)b * C_ + c0 + cl) * N_ + n0 + nl;
        float v = 0.f; unsigned m = 0;
        #pragma unroll
        for (int t = 0; t < T_; t++) {
            float xt = xp[(size_t)t * B_ * C_ * N_];
            v = v + (xt - v) * 0.5f;               // v += (x - v)/TAU, TAU=2
            if (v - 1.0f >= 0.f) { m |= 1u << t; v = 0.f; }
        }
        sm[cl * 68 + nl] = (unsigned char)m;
    }
    __syncthreads();
    #pragma unroll
    for (int i = 0; i < 16; i++) {
        int idx = i * 256 + tid;
        int cl = idx & 63, nl = idx >> 6;          // lanes -> consecutive c (coalesced)
        xs_mask[((size_t)b * N_ + n0 + nl) * C_ + c0 + cl] = sm[cl * 68 + nl];
    }
}

// ---------------- k2: sparse qkv GEMM + BN + LIF ----------------
// grid (N, B), block 384. Thread tid: group g=tid>>7 (q/k/v), owns 4 channels
// ch=(tid&127)*4; one float4 load per active row (384 lanes x 16B = full row).
__global__ __launch_bounds__(384) void
k2_qkv(const unsigned char* __restrict__ xs_mask,
       const float* __restrict__ wqkv_t,
       const float* __restrict__ bnc,
       unsigned char* __restrict__ q_mask,
       unsigned char* __restrict__ kvand_mask){
    __shared__ uint32 smask[128];                  // 512 bytes; reused as kbits buffer
    __shared__ uint32 scnt;
    __shared__ uint32 slist[512];
    int n = blockIdx.x, b = blockIdx.y, tid = threadIdx.x;
    size_t colbase = ((size_t)b * N_ + n) * C_;
    if (tid < 128) smask[tid] = reinterpret_cast<const uint32*>(xs_mask + colbase)[tid];
    if (tid == 0) scnt = 0;
    __syncthreads();
    if (tid < 256) {
        const unsigned char* smb = (const unsigned char*)smask;
        #pragma unroll
        for (int h = 0; h < 2; h++) {
            int c = tid + (h << 8);
            unsigned m = smb[c];
            if (m) { unsigned p = atomicAdd(&scnt, 1u); slist[p] = (unsigned)c | (m << 16); }
        }
    }
    __syncthreads();
    int cnt = scnt;

    int g = tid >> 7;                              // 0=q, 1=k, 2=v
    float acc[4][4];
    #pragma unroll
    for (int t = 0; t < 4; t++)
        #pragma unroll
        for (int i = 0; i < 4; i++) acc[t][i] = 0.f;

#define ACC4(t, w_) { acc[t][0]+=w_.x; acc[t][1]+=w_.y; acc[t][2]+=w_.z; acc[t][3]+=w_.w; }
    int j = 0;
    for (; j + 4 <= cnt; j += 4) {
        unsigned e0 = __builtin_amdgcn_readfirstlane(slist[j]);
        unsigned e1 = __builtin_amdgcn_readfirstlane(slist[j + 1]);
        unsigned e2 = __builtin_amdgcn_readfirstlane(slist[j + 2]);
        unsigned e3 = __builtin_amdgcn_readfirstlane(slist[j + 3]);
        float4 w0 = reinterpret_cast<const float4*>(wqkv_t + (size_t)(e0 & 0xffffu) * O3_)[tid];
        float4 w1 = reinterpret_cast<const float4*>(wqkv_t + (size_t)(e1 & 0xffffu) * O3_)[tid];
        float4 w2 = reinterpret_cast<const float4*>(wqkv_t + (size_t)(e2 & 0xffffu) * O3_)[tid];
        float4 w3 = reinterpret_cast<const float4*>(wqkv_t + (size_t)(e3 & 0xffffu) * O3_)[tid];
        unsigned m0 = e0 >> 16, m1 = e1 >> 16, m2 = e2 >> 16, m3 = e3 >> 16;
        if (m0 & 1u) ACC4(0, w0)  if (m0 & 2u) ACC4(1, w0)
        if (m0 & 4u) ACC4(2, w0)  if (m0 & 8u) ACC4(3, w0)
        if (m1 & 1u) ACC4(0, w1)  if (m1 & 2u) ACC4(1, w1)
        if (m1 & 4u) ACC4(2, w1)  if (m1 & 8u) ACC4(3, w1)
        if (m2 & 1u) ACC4(0, w2)  if (m2 & 2u) ACC4(1, w2)
        if (m2 & 4u) ACC4(2, w2)  if (m2 & 8u) ACC4(3, w2)
        if (m3 & 1u) ACC4(0, w3)  if (m3 & 2u) ACC4(1, w3)
        if (m3 & 4u) ACC4(2, w3)  if (m3 & 8u) ACC4(3, w3)
    }
    for (; j < cnt; j++) {
        unsigned e0 = __builtin_amdgcn_readfirstlane(slist[j]);
        float4 w0 = reinterpret_cast<const float4*>(wqkv_t + (size_t)(e0 & 0xffffu) * O3_)[tid];
        unsigned m0 = e0 >> 16;
        if (m0 & 1u) ACC4(0, w0)  if (m0 & 2u) ACC4(1, w0)
        if (m0 & 4u) ACC4(2, w0)  if (m0 & 8u) ACC4(3, w0)
    }
#undef ACC4

    // BN + LIF per owned channel; pack 4 channel-bytes into one uint.
    int chb = (tid & 127) * 4;
    unsigned packed = 0;
    #pragma unroll
    for (int i = 0; i < 4; i++) {
        int ch = chb + i;
        float inv = bnc[g * 1024 + ch];
        float sh  = bnc[g * 1024 + 512 + ch];
        float v = 0.f; unsigned bits = 0;
        #pragma unroll
        for (int t = 0; t < 4; t++) {
            float pre = acc[t][i] * inv + sh;      // BN
            v = v + (pre - v) * 0.5f;              // LIF
            if (v - 1.0f >= 0.f) { bits |= 1u << t; v = 0.f; }
        }
        packed |= bits << (8 * i);
    }
    if (g == 0)      reinterpret_cast<uint32*>(q_mask + colbase)[tid] = packed;
    else if (g == 1) smask[tid - 128] = packed;    // kbits exchange
    __syncthreads();
    if (g == 2) {
        unsigned kb = smask[tid - 256];
        reinterpret_cast<uint32*>(kvand_mask + colbase)[tid - 256] = packed & kb;
    }
}

// ---------------- k3: kv popcount over n + exact LIF ----------------
// grid (2, B), block 256 (lane = channel).
__global__ void k3_kv(const unsigned char* __restrict__ kvand_mask,
                      unsigned char* __restrict__ kvs_mask){
    int c = blockIdx.x * 256 + threadIdx.x;
    int b = blockIdx.y;
    int cnt[4] = {0, 0, 0, 0};
    const unsigned char* p = kvand_mask + (size_t)b * N_ * C_ + c;
    for (int n = 0; n < N_; n++) {
        unsigned m = p[(size_t)n * C_];
        #pragma unroll
        for (int t = 0; t < 4; t++) cnt[t] += (m >> t) & 1;
    }
    float v = 0.f; unsigned bits = 0;
    #pragma unroll
    for (int t = 0; t < 4; t++) {
        float kvf = (float)cnt[t];                 // counts exact in fp32
        v = v + (kvf - v) * 0.5f;
        if (v - 0.5f >= 0.f) { bits |= 1u << t; v = 0.f; }
    }
    kvs_mask[b * C_ + c] = (unsigned char)bits;
}

// ---------------- k4: sparse proj GEMM (attn = q & kv_s) + BN ----------------
// grid (N, B), block 128. Thread owns 4 channels (float4 per row).
__global__ __launch_bounds__(128) void
k4_attn_proj(const unsigned char* __restrict__ q_mask,
             const unsigned char* __restrict__ kvs_mask,
             const float* __restrict__ pwt,
             const float* __restrict__ bnc,
             float* __restrict__ y_t){
    __shared__ uint32 smask[128];
    __shared__ uint32 scnt;
    __shared__ uint32 slist[512];
    int n = blockIdx.x, b = blockIdx.y, tid = threadIdx.x;
    size_t colbase = ((size_t)b * N_ + n) * C_;
    {
        uint32 qm = reinterpret_cast<const uint32*>(q_mask + colbase)[tid];
        uint32 kv = reinterpret_cast<const uint32*>(kvs_mask + (size_t)b * C_)[tid];
        smask[tid] = qm & kv;
    }
    if (tid == 0) scnt = 0;
    __syncthreads();
    {
        const unsigned char* smb = (const unsigned char*)smask;
        #pragma unroll
        for (int h = 0; h < 4; h++) {
            int c = tid * 4 + h;
            unsigned m = smb[c];
            if (m) { unsigned p = atomicAdd(&scnt, 1u); slist[p] = (unsigned)c | (m << 16); }
        }
    }
    __syncthreads();
    int cnt = scnt;

    float acc[4][4];
    #pragma unroll
    for (int t = 0; t < 4; t++)
        #pragma unroll
        for (int i = 0; i < 4; i++) acc[t][i] = 0.f;

#define ACC4(t, w_) { acc[t][0]+=w_.x; acc[t][1]+=w_.y; acc[t][2]+=w_.z; acc[t][3]+=w_.w; }
    int j = 0;
    for (; j + 4 <= cnt; j += 4) {
        unsigned e0 = __builtin_amdgcn_readfirstlane(slist[j]);
        unsigned e1 = __builtin_amdgcn_readfirstlane(slist[j + 1]);
        unsigned e2 = __builtin_amdgcn_readfirstlane(slist[j + 2]);
        unsigned e3 = __builtin_amdgcn_readfirstlane(slist[j + 3]);
        float4 w0 = reinterpret_cast<const float4*>(pwt + (size_t)(e0 & 0xffffu) * C_)[tid];
        float4 w1 = reinterpret_cast<const float4*>(pwt + (size_t)(e1 & 0xffffu) * C_)[tid];
        float4 w2 = reinterpret_cast<const float4*>(pwt + (size_t)(e2 & 0xffffu) * C_)[tid];
        float4 w3 = reinterpret_cast<const float4*>(pwt + (size_t)(e3 & 0xffffu) * C_)[tid];
        unsigned m0 = e0 >> 16, m1 = e1 >> 16, m2 = e2 >> 16, m3 = e3 >> 16;
        if (m0 & 1u) ACC4(0, w0)  if (m0 & 2u) ACC4(1, w0)
        if (m0 & 4u) ACC4(2, w0)  if (m0 & 8u) ACC4(3, w0)
        if (m1 & 1u) ACC4(0, w1)  if (m1 & 2u) ACC4(1, w1)
        if (m1 & 4u) ACC4(2, w1)  if (m1 & 8u) ACC4(3, w1)
        if (m2 & 1u) ACC4(0, w2)  if (m2 & 2u) ACC4(1, w2)
        if (m2 & 4u) ACC4(2, w2)  if (m2 & 8u) ACC4(3, w2)
        if (m3 & 1u) ACC4(0, w3)  if (m3 & 2u) ACC4(1, w3)
        if (m3 & 4u) ACC4(2, w3)  if (m3 & 8u) ACC4(3, w3)
    }
    for (; j < cnt; j++) {
        unsigned e0 = __builtin_amdgcn_readfirstlane(slist[j]);
        float4 w0 = reinterpret_cast<const float4*>(pwt + (size_t)(e0 & 0xffffu) * C_)[tid];
        unsigned m0 = e0 >> 16;
        if (m0 & 1u) ACC4(0, w0)  if (m0 & 2u) ACC4(1, w0)
        if (m0 & 4u) ACC4(2, w0)  if (m0 & 8u) ACC4(3, w0)
    }
#undef ACC4

    float4 inv = reinterpret_cast<const float4*>(bnc + 3072)[tid];
    float4 sh  = reinterpret_cast<const float4*>(bnc + 3584)[tid];
    #pragma unroll
    for (int t = 0; t < 4; t++) {
        float4 y4;
        y4.x = acc[t][0] * inv.x + sh.x;
        y4.y = acc[t][1] * inv.y + sh.y;
        y4.z = acc[t][2] * inv.z + sh.z;
        y4.w = acc[t][3] * inv.w + sh.w;
        reinterpret_cast<float4*>(y_t + (((size_t)t * B_ + b) * N_ + n) * C_)[tid] = y4;
    }
}

// ---------------- k5: transpose back + identity add ----------------
// grid (B, C/64, N/64), block 256.
__global__ void k5_out(const float* __restrict__ y_t, const float* __restrict__ x,
                       float* __restrict__ out){
    __shared__ float tile[64 * 65];
    int b = blockIdx.x, o0 = blockIdx.y * 64, n0 = blockIdx.z * 64;
    int tid = threadIdx.x;
    for (int t = 0; t < T_; t++) {
        __syncthreads();
        #pragma unroll
        for (int i = 0; i < 16; i++) {
            int idx = i * 256 + tid;
            int ol = idx & 63, nl = idx >> 6;      // lanes -> consecutive o (coalesced read)
            tile[ol * 65 + nl] =
                y_t[(((size_t)t * B_ + b) * N_ + n0 + nl) * C_ + o0 + ol];
        }
        __syncthreads();
        #pragma unroll
        for (int i = 0; i < 16; i++) {
            int idx = i * 256 + tid;
            int nl = idx & 63, ol = idx >> 6;      // lanes -> consecutive n (coalesced write)
            size_t a = (((size_t)t * B_ + b) * C_ + o0 + ol) * N_ + n0 + nl;
            out[a] = tile[ol * 65 + nl] + x[a];
        }
    }
}

extern "C" void kernel_launch(void* const* d_in, const int* in_sizes, int n_in,
                              void* d_out, int out_size, void* d_ws, size_t ws_size,
                              hipStream_t stream){
    const float* x     = (const float*)d_in[0];
    const float* q_w   = (const float*)d_in[1];
    const float* q_g   = (const float*)d_in[2];
    const float* q_b   = (const float*)d_in[3];
    const float* q_m   = (const float*)d_in[4];
    const float* q_v   = (const float*)d_in[5];
    const float* k_w   = (const float*)d_in[6];
    const float* k_g   = (const float*)d_in[7];
    const float* k_b   = (const float*)d_in[8];
    const float* k_m   = (const float*)d_in[9];
    const float* k_v   = (const float*)d_in[10];
    const float* v_w   = (const float*)d_in[11];
    const float* v_g   = (const float*)d_in[12];
    const float* v_b   = (const float*)d_in[13];
    const float* v_m   = (const float*)d_in[14];
    const float* v_v   = (const float*)d_in[15];
    const float* pr_w  = (const float*)d_in[16];
    const float* pr_b  = (const float*)d_in[17];
    const float* p_g   = (const float*)d_in[18];
    const float* p_b2  = (const float*)d_in[19];
    const float* p_m   = (const float*)d_in[20];
    const float* p_v   = (const float*)d_in[21];
    float* out = (float*)d_out;

    char* ws = (char*)d_ws;
    float* wqkv_t          = (float*)(ws + 0);                 // 3,145,728
    float* pwt             = (float*)(ws + 3145728);           // 1,048,576
    float* bnc             = (float*)(ws + 4194304);           //    16,384
    unsigned char* xs_mask = (unsigned char*)(ws + 4210688);   // 2,097,152
    unsigned char* q_mask  = (unsigned char*)(ws + 6307840);   // 2,097,152
    unsigned char* kvand   = (unsigned char*)(ws + 8404992);   // 2,097,152
    unsigned char* kvs     = (unsigned char*)(ws + 10502144);  //     8,192
    float* y_t             = (float*)(ws + 10510336);          // 33,554,432 -> ~44 MB

    hipLaunchKernelGGL(k0_prep, dim3(258), dim3(256), 0, stream,
                       q_w, k_w, v_w, pr_w,
                       q_g,q_b,q_m,q_v, k_g,k_b,k_m,k_v, v_g,v_b,v_m,v_v,
                       p_g,p_b2,p_m,p_v, pr_b, wqkv_t, pwt, bnc);
    hipLaunchKernelGGL(k1_lif_x, dim3(B_, C_/64, N_/64), dim3(256), 0, stream, x, xs_mask);
    hipLaunchKernelGGL(k2_qkv, dim3(N_, B_), dim3(384), 0, stream,
                       xs_mask, wqkv_t, bnc, q_mask, kvand);
    hipLaunchKernelGGL(k3_kv, dim3(2, B_), dim3(256), 0, stream, kvand, kvs);
    hipLaunchKernelGGL(k4_attn_proj, dim3(N_, B_), dim3(128), 0, stream,
                       q_mask, kvs, pwt, bnc, y_t);
    hipLaunchKernelGGL(k5_out, dim3(B_, C_/64, N_/64), dim3(256), 0, stream, y_t, x, out);
}